// Round 5
// baseline (127.705 us; speedup 1.0000x reference)
//
#include <hip/hip_runtime.h>
#include <math.h>

#define EPS   1e-6f
#define K_V   0.4052847345693511f   /* 4/pi^2 */
#define IMG2  369664.0f             /* 608^2 */
#define NBOX  150
#define NBOXP 152                   /* padded so each quarter is exactly 38 */
#define NCLS  20

// 64 anchors per block, 4 lanes per anchor (quarter q scans boxes q*38..q*38+37)
#define BPB_L0 271   /* ceil(17328/64) */
#define BPB_L1 68    /* ceil(4332/64)  */
#define BPB_L2 17    /* ceil(1083/64)  */
#define NBLK   (4*(BPB_L0+BPB_L1+BPB_L2))   /* 1424 */

#define NDW_P  1600   /* 64 rows * 25 */
#define NDW_LB 1664   /* 64 rows * 26 */

__device__ __forceinline__ float fast_rcp(float x) { return __builtin_amdgcn_rcpf(x); }

__device__ __forceinline__ float bce_logits(float x, float t) {
    // logaddexp(0,x) - x*t via hw exp/log; |err| ~1e-7*|val|, threshold is 591.
    float e = __expf(-fabsf(x));
    return fmaxf(x, 0.f) + __logf(1.f + e) - x * t;
}

__device__ __forceinline__ float wave_sum(float v) {
#pragma unroll
    for (int off = 32; off > 0; off >>= 1) v += __shfl_down(v, off, 64);
    return v;
}

__global__ __launch_bounds__(256, 6) void yolo_loss_kernel(
    const float* __restrict__ p0,  const float* __restrict__ pd0,
    const float* __restrict__ lb0, const float* __restrict__ bb0,
    const float* __restrict__ p1,  const float* __restrict__ pd1,
    const float* __restrict__ lb1, const float* __restrict__ bb1,
    const float* __restrict__ p2,  const float* __restrict__ pd2,
    const float* __restrict__ lb2, const float* __restrict__ bb2,
    float* __restrict__ ws, float* __restrict__ out)
{
    __shared__ float  s_pd[NDW_P], s_lb[NDW_LB], s_p[NDW_P];
    __shared__ float4 s_box[NBOXP];   // lox, loy, hix, hiy
    __shared__ float4 s_aux[NBOXP];   // area, cx, cy, atan(w/h)
    __shared__ float  s_part[4][3];

    const int blk = blockIdx.x;
    const float *p, *pd, *lb, *bb;
    int batch, lblk, apb;
    if (blk < 4*BPB_L0) {
        p = p0; pd = pd0; lb = lb0; bb = bb0;
        batch = blk / BPB_L0; lblk = blk % BPB_L0; apb = 17328;
    } else if (blk < 4*(BPB_L0+BPB_L1)) {
        int r = blk - 4*BPB_L0;
        p = p1; pd = pd1; lb = lb1; bb = bb1;
        batch = r / BPB_L1; lblk = r % BPB_L1; apb = 4332;
    } else {
        int r = blk - 4*(BPB_L0+BPB_L1);
        p = p2; pd = pd2; lb = lb2; bb = bb2;
        batch = r / BPB_L2; lblk = r % BPB_L2; apb = 1083;
    }

    const int tid = threadIdx.x;
    const int navail = min(64, apb - lblk * 64);
    const size_t base0 = (size_t)batch * apb + (size_t)lblk * 64;

    // ---- cooperative, fully-coalesced staging of this block's 64 AoS rows.
    // All 21 global loads issue before any use -> latency drained at BW.
    const float* gpd = pd + base0 * 25;
    const float* glb = lb + base0 * 26;
    const float* gp  = p  + base0 * 25;
    const int ndw_p  = navail * 25;
    const int ndw_lb = navail * 26;

    float vpd[7], vlb[7], vp[7];
#pragma unroll
    for (int i = 0; i < 7; ++i) { int idx = tid + i*256; vpd[i] = (idx < ndw_p)  ? gpd[idx] : 0.f; }
#pragma unroll
    for (int i = 0; i < 7; ++i) { int idx = tid + i*256; vlb[i] = (idx < ndw_lb) ? glb[idx] : 0.f; }
#pragma unroll
    for (int i = 0; i < 7; ++i) { int idx = tid + i*256; vp[i]  = (idx < ndw_p)  ? gp[idx]  : 0.f; }

    // gt boxes (150 + 2 degenerate pads)
    float4 bxy = make_float4(3.0e30f, 3.0e30f, 0.f, 1.f);
    if (tid < NBOX) bxy = ((const float4*)bb)[batch * NBOX + tid];  // 16B aligned

#pragma unroll
    for (int i = 0; i < 7; ++i) { int idx = tid + i*256; if (idx < NDW_P)  s_pd[idx] = vpd[i]; }
#pragma unroll
    for (int i = 0; i < 7; ++i) { int idx = tid + i*256; if (idx < NDW_LB) s_lb[idx] = vlb[i]; }
#pragma unroll
    for (int i = 0; i < 7; ++i) { int idx = tid + i*256; if (idx < NDW_P)  s_p[idx]  = vp[i]; }

    if (tid < NBOXP) {
        float hw = bxy.z * 0.5f, hh = bxy.w * 0.5f;
        float ltx = bxy.x - hw, lty = bxy.y - hh, rbx = bxy.x + hw, rby = bxy.y + hh;
        float lox = fminf(ltx, rbx), hix = fmaxf(ltx, rbx);
        float loy = fminf(lty, rby), hiy = fmaxf(lty, rby);
        s_box[tid] = make_float4(lox, loy, hix, hiy);
        s_aux[tid] = make_float4((hix - lox) * (hiy - loy), bxy.x, bxy.y,
                                 atanf(bxy.z / fmaxf(bxy.w, EPS)));
    }
    __syncthreads();

    const int wave = tid >> 6, lane = tid & 63;
    const int q = lane >> 4, s = lane & 15;          // 4 lanes per anchor
    const int row = wave * 16 + s;                   // anchor index in block
    const bool active = (row < navail);
    const size_t base = base0 + row;

    // per-anchor fields from LDS (zeros for tail rows -> all outputs gated)
    const float b1x = s_pd[row*25 + 0], b1y = s_pd[row*25 + 1];
    const float b1w = s_pd[row*25 + 2], b1h = s_pd[row*25 + 3];
    const float obj = s_lb[row*26 + 4], mix = s_lb[row*26 + 5];
    const float pconf = s_p[row*25 + 4];

    const float hw = b1w * 0.5f, hh = b1h * 0.5f;
    const float l1x = b1x - hw, l1y = b1y - hh;
    const float r1x = b1x + hw, r1y = b1y + hh;
    const float lo1x = fminf(l1x, r1x), hi1x = fmaxf(l1x, r1x);
    const float lo1y = fminf(l1y, r1y), hi1y = fmaxf(l1y, r1y);
    const float area1 = (hi1x - lo1x) * (hi1y - lo1y);

    // ---- phase 1: division-free pre-test over this quarter's 38 boxes.
    // 2*inter >= (1-4e-6)*max(union,EPS) is necessary for fl(inter/union)>=0.5
    // (and ciou <= iou always). Flagged pairs recorded in a per-lane bitmask.
    const int j0 = q * 38;
    unsigned long long mask = 0ull;
    if (obj == 0.f) {
#pragma unroll 4
        for (int k = 0; k < 38; ++k) {
            float4 b4 = s_box[j0 + k];
            float a2  = s_aux[j0 + k].x;
            float ix0 = fmaxf(lo1x, b4.x), iy0 = fmaxf(lo1y, b4.y);
            float ix1 = fminf(hi1x, b4.z), iy1 = fminf(hi1y, b4.w);
            float iwx = fmaxf(ix1 - ix0, 0.f);
            float iwy = fmaxf(iy1 - iy0, 0.f);
            float inter = iwx * iwy;
            float uni_m = fmaxf(area1 + a2 - inter, EPS);
            float metric = fmaf(-0.999996f, uni_m, inter + inter);
            mask |= (unsigned long long)(metric > 0.f) << k;
        }
    }

    // ---- phase 2: exact ciou >= 0.5 only for flagged pairs (rare)
    int hit = 0;
    if (mask) {
        const float at1 = atanf(b1w / fmaxf(b1h, EPS));
        unsigned long long m = mask;
        do {
            int k = __ffsll(m) - 1; m &= m - 1;
            float4 b4 = s_box[j0 + k];
            float4 ax = s_aux[j0 + k];
            float ix0 = fmaxf(lo1x, b4.x), iy0 = fmaxf(lo1y, b4.y);
            float ix1 = fminf(hi1x, b4.z), iy1 = fminf(hi1y, b4.w);
            float iwx = fmaxf(ix1 - ix0, 0.f);
            float iwy = fmaxf(iy1 - iy0, 0.f);
            float inter = iwx * iwy;
            float iou = inter * fast_rcp(fmaxf(area1 + ax.x - inter, EPS));
            float owx = fmaxf(hi1x, b4.z) - fminf(lo1x, b4.x);
            float owy = fmaxf(hi1y, b4.w) - fminf(lo1y, b4.y);
            float c2 = fmaxf(owx * owx + owy * owy, EPS);
            float dx = b1x - ax.y, dy = b1y - ax.z;
            float u = (dx * dx + dy * dy) * fast_rcp(c2);
            float dv = ax.w - at1;
            float v = K_V * dv * dv;
            float alpha = v * fast_rcp(fmaxf(1.f - iou + v, EPS));
            float ci = iou - (u + alpha * v);
            hit |= (ci >= 0.5f);
        } while (m);
    }
    hit |= __shfl_xor(hit, 16, 64);   // combine the 4 box quarters
    hit |= __shfl_xor(hit, 32, 64);

    // ---- per-anchor outputs
    float t_ciou = 0.f, t_conf = 0.f, t_cls = 0.f;
    if (active && obj > 0.f) {
        // class BCE split across the 4 quarter-lanes (5 classes each); the
        // wave reduction sums the partials exactly once.
        float cs = 0.f;
#pragma unroll
        for (int c = 0; c < 5; ++c) {
            int cc = q * 5 + c;
            cs += bce_logits(s_p[row*25 + 5 + cc], s_lb[row*26 + 6 + cc]);
        }
        t_cls = cs * mix;
    }
    if (active && q == 0) {
        const float sig = fast_rcp(1.f + __expf(-pconf));
        const float dd = fabsf(obj - sig);
        const float focal = bce_logits(pconf, obj) * (dd * dd); // ALPHA=1,GAMMA=2
        float gate;
        if (obj > 0.f) {
            const float at1 = atanf(b1w / fmaxf(b1h, EPS));
            const float lx = s_lb[row*26 + 0], ly = s_lb[row*26 + 1];
            const float lw = s_lb[row*26 + 2], lh = s_lb[row*26 + 3];
            const float hlw = lw * 0.5f, hlh = lh * 0.5f;
            const float l2x = lx - hlw, l2y = ly - hlh;
            const float r2x = lx + hlw, r2y = ly + hlh;
            const float lo2x = fminf(l2x, r2x), hi2x = fmaxf(l2x, r2x);
            const float lo2y = fminf(l2y, r2y), hi2y = fmaxf(l2y, r2y);
            const float area2 = (hi2x - lo2x) * (hi2y - lo2y);
            float iwx = fmaxf(fminf(hi1x, hi2x) - fmaxf(lo1x, lo2x), 0.f);
            float iwy = fmaxf(fminf(hi1y, hi2y) - fmaxf(lo1y, lo2y), 0.f);
            float inter = iwx * iwy;
            float iou = inter * fast_rcp(fmaxf(area1 + area2 - inter, EPS));
            float owx = fmaxf(hi1x, hi2x) - fminf(lo1x, lo2x);
            float owy = fmaxf(hi1y, hi2y) - fminf(lo1y, lo2y);
            float c2 = fmaxf(owx * owx + owy * owy, EPS);
            float dx = b1x - lx, dy = b1y - ly;
            float u = (dx * dx + dy * dy) * fast_rcp(c2);
            float at2 = atanf(lw / fmaxf(lh, EPS));
            float dv = at2 - at1;
            float v = K_V * dv * dv;
            float alpha = v * fast_rcp(fmaxf(1.f - iou + v, EPS));
            float ciou = iou - (u + alpha * v);

            float scale = 2.f - lw * lh * (1.f / IMG2);
            t_ciou = scale * (1.f - ciou) * mix;
            gate = 1.f;
        } else {
            gate = hit ? 0.f : 1.f;
        }
        t_conf = gate * focal * mix;
    }

    // ---- block reduction: wave shuffle -> LDS -> 3 atomics per block
    float r0 = wave_sum(t_ciou);
    float r1 = wave_sum(t_conf);
    float r2 = wave_sum(t_cls);
    if (lane == 0) { s_part[wave][0] = r0; s_part[wave][1] = r1; s_part[wave][2] = r2; }
    __syncthreads();

    if (tid == 0) {
        float c = 0.f, f = 0.f, cl = 0.f;
#pragma unroll
        for (int w = 0; w < 4; ++w) { c += s_part[w][0]; f += s_part[w][1]; cl += s_part[w][2]; }
        const int slot = (blk & 7) * 16;      // 8 XCD-strided slots, 64B apart
        atomicAdd(&ws[slot + 0], c);
        atomicAdd(&ws[slot + 1], f);
        atomicAdd(&ws[slot + 2], cl);
        __threadfence();
        unsigned old = atomicAdd((unsigned*)(ws + 128), 1u);
        if (old == NBLK - 1) {
            __threadfence();
            float C = 0.f, F = 0.f, CL = 0.f;
#pragma unroll
            for (int sl = 0; sl < 8; ++sl) {
                C  += atomicAdd(&ws[sl*16 + 0], 0.f);   // coherent L2 reads
                F  += atomicAdd(&ws[sl*16 + 1], 0.f);
                CL += atomicAdd(&ws[sl*16 + 2], 0.f);
            }
            const float inv_bs = 0.25f;   // bs = 4 for every layer
            out[0] = (C + F + CL) * inv_bs;
            out[1] = C * inv_bs;
            out[2] = F * inv_bs;
            out[3] = CL * inv_bs;
        }
    }
}

extern "C" void kernel_launch(void* const* d_in, const int* in_sizes, int n_in,
                              void* d_out, int out_size, void* d_ws, size_t ws_size,
                              hipStream_t stream) {
    const float* p0  = (const float*)d_in[0];
    const float* pd0 = (const float*)d_in[1];
    const float* lb0 = (const float*)d_in[2];
    const float* bb0 = (const float*)d_in[3];
    const float* p1  = (const float*)d_in[4];
    const float* pd1 = (const float*)d_in[5];
    const float* lb1 = (const float*)d_in[6];
    const float* bb1 = (const float*)d_in[7];
    const float* p2  = (const float*)d_in[8];
    const float* pd2 = (const float*)d_in[9];
    const float* lb2 = (const float*)d_in[10];
    const float* bb2 = (const float*)d_in[11];

    float* ws = (float*)d_ws;
    hipMemsetAsync(ws, 0, 132 * sizeof(float), stream);  // 8 slots + counter

    yolo_loss_kernel<<<NBLK, 256, 0, stream>>>(
        p0, pd0, lb0, bb0, p1, pd1, lb1, bb1, p2, pd2, lb2, bb2,
        ws, (float*)d_out);
}

// Round 6
// 127.418 us; speedup vs baseline: 1.0022x; 1.0022x over previous
//
#include <hip/hip_runtime.h>
#include <math.h>

#define EPS   1e-6f
#define K_V   0.4052847345693511f   /* 4/pi^2 */
#define IMG2  369664.0f             /* 608^2 */
#define NBOX  150
#define NBOXP 152                   /* padded so each quarter is exactly 38 */
#define NCLS  20

// 64 anchors per block, 4 lanes per anchor (quarter q scans boxes q*38..q*38+37)
#define BPB_L0 271   /* ceil(17328/64) */
#define BPB_L1 68    /* ceil(4332/64)  */
#define BPB_L2 17    /* ceil(1083/64)  */
#define NBLK   (4*(BPB_L0+BPB_L1+BPB_L2))   /* 1424 */

#define NDW_P  1600   /* 64 rows * 25 */
#define NDW_LB 1664   /* 64 rows * 26 */

__device__ __forceinline__ float fast_rcp(float x) { return __builtin_amdgcn_rcpf(x); }

__device__ __forceinline__ float bce_logits(float x, float t) {
    // logaddexp(0,x) - x*t via hw exp/log; |err| ~1e-7*|val|, threshold is 591.
    float e = __expf(-fabsf(x));
    return fmaxf(x, 0.f) + __logf(1.f + e) - x * t;
}

__device__ __forceinline__ float wave_sum(float v) {
#pragma unroll
    for (int off = 32; off > 0; off >>= 1) v += __shfl_down(v, off, 64);
    return v;
}

// Stage ndw dwords (multiple of 64) g[0..ndw) -> s[0..ndw), one wave-chunk
// (64 dwords) per global_load_lds issue: LDS dest = wave-uniform base +
// lane*4, global src = per-lane. No VGPR round-trip, no data registers.
// Chunks that would read past the layer array end (g0+base+64 > tot: only
// the 3 layer-final blocks) fall back to predicated scalar loads.
__device__ __forceinline__ void stage(const float* __restrict__ g, float* s,
                                      size_t g0, size_t tot, int ndw,
                                      int wave, int lane) {
    for (int base = wave * 64; base < ndw; base += 256) {
        if (g0 + base + 64 <= tot) {
            __builtin_amdgcn_global_load_lds(
                (const __attribute__((address_space(1))) void*)(g + base + lane),
                (__attribute__((address_space(3))) void*)(s + base), 4, 0, 0);
        } else {
            int idx = base + lane;
            s[idx] = (g0 + idx < tot) ? g[idx] : 0.f;
        }
    }
}

__global__ __launch_bounds__(256, 6) void yolo_loss_kernel(
    const float* __restrict__ p0,  const float* __restrict__ pd0,
    const float* __restrict__ lb0, const float* __restrict__ bb0,
    const float* __restrict__ p1,  const float* __restrict__ pd1,
    const float* __restrict__ lb1, const float* __restrict__ bb1,
    const float* __restrict__ p2,  const float* __restrict__ pd2,
    const float* __restrict__ lb2, const float* __restrict__ bb2,
    float* __restrict__ ws, float* __restrict__ out)
{
    __shared__ float  s_pd[NDW_P], s_lb[NDW_LB], s_p[NDW_P];
    __shared__ float4 s_box[NBOXP];   // lox, loy, hix, hiy
    __shared__ float4 s_aux[NBOXP];   // area, cx, cy, atan(w/h)
    __shared__ float  s_part[4][3];

    const int blk = blockIdx.x;
    const float *p, *pd, *lb, *bb;
    int batch, lblk, apb;
    if (blk < 4*BPB_L0) {
        p = p0; pd = pd0; lb = lb0; bb = bb0;
        batch = blk / BPB_L0; lblk = blk % BPB_L0; apb = 17328;
    } else if (blk < 4*(BPB_L0+BPB_L1)) {
        int r = blk - 4*BPB_L0;
        p = p1; pd = pd1; lb = lb1; bb = bb1;
        batch = r / BPB_L1; lblk = r % BPB_L1; apb = 4332;
    } else {
        int r = blk - 4*(BPB_L0+BPB_L1);
        p = p2; pd = pd2; lb = lb2; bb = bb2;
        batch = r / BPB_L2; lblk = r % BPB_L2; apb = 1083;
    }

    const int tid  = threadIdx.x;
    const int wave = tid >> 6, lane = tid & 63;
    const int navail = min(64, apb - lblk * 64);
    const size_t base0 = (size_t)batch * apb + (size_t)lblk * 64;

    // ---- async coalesced staging of this block's 64 AoS rows into LDS.
    // Rows >= navail may stage garbage (next batch / zeros) — all outputs
    // are gated by `active` below.
    const size_t g0p  = base0 * 25, g0lb = base0 * 26;
    const size_t totp = (size_t)apb * 100;    // 4 batches * apb * 25 dwords
    const size_t totlb = (size_t)apb * 104;   // 4 batches * apb * 26 dwords
    stage(pd + g0p,  s_pd, g0p,  totp,  NDW_P,  wave, lane);
    stage(lb + g0lb, s_lb, g0lb, totlb, NDW_LB, wave, lane);
    stage(p + g0p,   s_p,  g0p,  totp,  NDW_P,  wave, lane);

    // gt boxes (150 + 2 degenerate pads)
    if (tid < NBOXP) {
        float4 bxy = make_float4(3.0e30f, 3.0e30f, 0.f, 1.f);
        if (tid < NBOX) bxy = ((const float4*)bb)[batch * NBOX + tid];  // 16B aligned
        float hw = bxy.z * 0.5f, hh = bxy.w * 0.5f;
        float ltx = bxy.x - hw, lty = bxy.y - hh, rbx = bxy.x + hw, rby = bxy.y + hh;
        float lox = fminf(ltx, rbx), hix = fmaxf(ltx, rbx);
        float loy = fminf(lty, rby), hiy = fmaxf(lty, rby);
        s_box[tid] = make_float4(lox, loy, hix, hiy);
        s_aux[tid] = make_float4((hix - lox) * (hiy - loy), bxy.x, bxy.y,
                                 atanf(bxy.z / fmaxf(bxy.w, EPS)));
    }
    __syncthreads();   // drains vmcnt (incl. global_load_lds) + lgkmcnt

    const int q = lane >> 4, s = lane & 15;          // 4 lanes per anchor
    const int row = wave * 16 + s;                   // anchor index in block
    const bool active = (row < navail);

    // per-anchor fields from LDS
    const float b1x = s_pd[row*25 + 0], b1y = s_pd[row*25 + 1];
    const float b1w = s_pd[row*25 + 2], b1h = s_pd[row*25 + 3];
    const float obj = s_lb[row*26 + 4], mix = s_lb[row*26 + 5];
    const float pconf = s_p[row*25 + 4];

    const float hw = b1w * 0.5f, hh = b1h * 0.5f;
    const float l1x = b1x - hw, l1y = b1y - hh;
    const float r1x = b1x + hw, r1y = b1y + hh;
    const float lo1x = fminf(l1x, r1x), hi1x = fmaxf(l1x, r1x);
    const float lo1y = fminf(l1y, r1y), hi1y = fmaxf(l1y, r1y);
    const float area1 = (hi1x - lo1x) * (hi1y - lo1y);

    // ---- phase 1: division-free pre-test over this quarter's 38 boxes.
    // 2*inter >= (1-4e-6)*max(union,EPS) is necessary for fl(inter/union)>=0.5
    // (and ciou <= iou always). Flagged pairs recorded in a per-lane bitmask.
    const int j0 = q * 38;
    unsigned long long mask = 0ull;
    if (active && obj == 0.f) {
#pragma unroll 4
        for (int k = 0; k < 38; ++k) {
            float4 b4 = s_box[j0 + k];
            float a2  = s_aux[j0 + k].x;
            float ix0 = fmaxf(lo1x, b4.x), iy0 = fmaxf(lo1y, b4.y);
            float ix1 = fminf(hi1x, b4.z), iy1 = fminf(hi1y, b4.w);
            float iwx = fmaxf(ix1 - ix0, 0.f);
            float iwy = fmaxf(iy1 - iy0, 0.f);
            float inter = iwx * iwy;
            float uni_m = fmaxf(area1 + a2 - inter, EPS);
            float metric = fmaf(-0.999996f, uni_m, inter + inter);
            mask |= (unsigned long long)(metric > 0.f) << k;
        }
    }

    // ---- phase 2: exact ciou >= 0.5 only for flagged pairs (rare)
    int hit = 0;
    if (mask) {
        const float at1 = atanf(b1w / fmaxf(b1h, EPS));
        unsigned long long m = mask;
        do {
            int k = __ffsll(m) - 1; m &= m - 1;
            float4 b4 = s_box[j0 + k];
            float4 ax = s_aux[j0 + k];
            float ix0 = fmaxf(lo1x, b4.x), iy0 = fmaxf(lo1y, b4.y);
            float ix1 = fminf(hi1x, b4.z), iy1 = fminf(hi1y, b4.w);
            float iwx = fmaxf(ix1 - ix0, 0.f);
            float iwy = fmaxf(iy1 - iy0, 0.f);
            float inter = iwx * iwy;
            float iou = inter * fast_rcp(fmaxf(area1 + ax.x - inter, EPS));
            float owx = fmaxf(hi1x, b4.z) - fminf(lo1x, b4.x);
            float owy = fmaxf(hi1y, b4.w) - fminf(lo1y, b4.y);
            float c2 = fmaxf(owx * owx + owy * owy, EPS);
            float dx = b1x - ax.y, dy = b1y - ax.z;
            float u = (dx * dx + dy * dy) * fast_rcp(c2);
            float dv = ax.w - at1;
            float v = K_V * dv * dv;
            float alpha = v * fast_rcp(fmaxf(1.f - iou + v, EPS));
            float ci = iou - (u + alpha * v);
            hit |= (ci >= 0.5f);
        } while (m);
    }
    hit |= __shfl_xor(hit, 16, 64);   // combine the 4 box quarters
    hit |= __shfl_xor(hit, 32, 64);

    // ---- per-anchor outputs
    float t_ciou = 0.f, t_conf = 0.f, t_cls = 0.f;
    if (active && obj > 0.f) {
        // class BCE split across the 4 quarter-lanes (5 classes each); the
        // wave reduction sums the partials exactly once.
        float cs = 0.f;
#pragma unroll
        for (int c = 0; c < 5; ++c) {
            int cc = q * 5 + c;
            cs += bce_logits(s_p[row*25 + 5 + cc], s_lb[row*26 + 6 + cc]);
        }
        t_cls = cs * mix;
    }
    if (active && q == 0) {
        const float sig = fast_rcp(1.f + __expf(-pconf));
        const float dd = fabsf(obj - sig);
        const float focal = bce_logits(pconf, obj) * (dd * dd); // ALPHA=1,GAMMA=2
        float gate;
        if (obj > 0.f) {
            const float at1 = atanf(b1w / fmaxf(b1h, EPS));
            const float lx = s_lb[row*26 + 0], ly = s_lb[row*26 + 1];
            const float lw = s_lb[row*26 + 2], lh = s_lb[row*26 + 3];
            const float hlw = lw * 0.5f, hlh = lh * 0.5f;
            const float l2x = lx - hlw, l2y = ly - hlh;
            const float r2x = lx + hlw, r2y = ly + hlh;
            const float lo2x = fminf(l2x, r2x), hi2x = fmaxf(l2x, r2x);
            const float lo2y = fminf(l2y, r2y), hi2y = fmaxf(l2y, r2y);
            const float area2 = (hi2x - lo2x) * (hi2y - lo2y);
            float iwx = fmaxf(fminf(hi1x, hi2x) - fmaxf(lo1x, lo2x), 0.f);
            float iwy = fmaxf(fminf(hi1y, hi2y) - fmaxf(lo1y, lo2y), 0.f);
            float inter = iwx * iwy;
            float iou = inter * fast_rcp(fmaxf(area1 + area2 - inter, EPS));
            float owx = fmaxf(hi1x, hi2x) - fminf(lo1x, lo2x);
            float owy = fmaxf(hi1y, hi2y) - fminf(lo1y, lo2y);
            float c2 = fmaxf(owx * owx + owy * owy, EPS);
            float dx = b1x - lx, dy = b1y - ly;
            float u = (dx * dx + dy * dy) * fast_rcp(c2);
            float at2 = atanf(lw / fmaxf(lh, EPS));
            float dv = at2 - at1;
            float v = K_V * dv * dv;
            float alpha = v * fast_rcp(fmaxf(1.f - iou + v, EPS));
            float ciou = iou - (u + alpha * v);

            float scale = 2.f - lw * lh * (1.f / IMG2);
            t_ciou = scale * (1.f - ciou) * mix;
            gate = 1.f;
        } else {
            gate = hit ? 0.f : 1.f;
        }
        t_conf = gate * focal * mix;
    }

    // ---- block reduction: wave shuffle -> LDS -> 3 atomics per block
    float r0 = wave_sum(t_ciou);
    float r1 = wave_sum(t_conf);
    float r2 = wave_sum(t_cls);
    if (lane == 0) { s_part[wave][0] = r0; s_part[wave][1] = r1; s_part[wave][2] = r2; }
    __syncthreads();

    if (tid == 0) {
        float c = 0.f, f = 0.f, cl = 0.f;
#pragma unroll
        for (int w = 0; w < 4; ++w) { c += s_part[w][0]; f += s_part[w][1]; cl += s_part[w][2]; }
        const int slot = (blk & 7) * 16;      // 8 XCD-strided slots, 64B apart
        atomicAdd(&ws[slot + 0], c);
        atomicAdd(&ws[slot + 1], f);
        atomicAdd(&ws[slot + 2], cl);
        __threadfence();
        unsigned old = atomicAdd((unsigned*)(ws + 128), 1u);
        if (old == NBLK - 1) {
            __threadfence();
            float C = 0.f, F = 0.f, CL = 0.f;
#pragma unroll
            for (int sl = 0; sl < 8; ++sl) {
                C  += atomicAdd(&ws[sl*16 + 0], 0.f);   // coherent L2 reads
                F  += atomicAdd(&ws[sl*16 + 1], 0.f);
                CL += atomicAdd(&ws[sl*16 + 2], 0.f);
            }
            const float inv_bs = 0.25f;   // bs = 4 for every layer
            out[0] = (C + F + CL) * inv_bs;
            out[1] = C * inv_bs;
            out[2] = F * inv_bs;
            out[3] = CL * inv_bs;
        }
    }
}

extern "C" void kernel_launch(void* const* d_in, const int* in_sizes, int n_in,
                              void* d_out, int out_size, void* d_ws, size_t ws_size,
                              hipStream_t stream) {
    const float* p0  = (const float*)d_in[0];
    const float* pd0 = (const float*)d_in[1];
    const float* lb0 = (const float*)d_in[2];
    const float* bb0 = (const float*)d_in[3];
    const float* p1  = (const float*)d_in[4];
    const float* pd1 = (const float*)d_in[5];
    const float* lb1 = (const float*)d_in[6];
    const float* bb1 = (const float*)d_in[7];
    const float* p2  = (const float*)d_in[8];
    const float* pd2 = (const float*)d_in[9];
    const float* lb2 = (const float*)d_in[10];
    const float* bb2 = (const float*)d_in[11];

    float* ws = (float*)d_ws;
    hipMemsetAsync(ws, 0, 132 * sizeof(float), stream);  // 8 slots + counter

    yolo_loss_kernel<<<NBLK, 256, 0, stream>>>(
        p0, pd0, lb0, bb0, p1, pd1, lb1, bb1, p2, pd2, lb2, bb2,
        ws, (float*)d_out);
}